// Round 14
// baseline (427.595 us; speedup 1.0000x reference)
//
#include <hip/hip_runtime.h>
#include <math.h>

#define BATCH  8192
#define TSTEPS 50
#define PTS    32          // points per block
#define NTHR   768         // 12 waves, 1 block/CU
#define KSTR   168         // P lds row stride (bf16 elems)
#define GKSTR  160         // global Wb row stride (bf16, 144 real + 16 zero)
#define TABSTR 100         // tabs row stride (f32)
#define QSTR   5           // qs row stride (coprime 32 -> conflict-free)
#define NROW   96          // GEMM N rows = PTS*3
#define PI_F   3.14159265358979323846f

typedef __bf16 bf16x8 __attribute__((ext_vector_type(8)));
typedef float  f32x4  __attribute__((ext_vector_type(4)));

__device__ __forceinline__ unsigned pack2bf(float a, float b) {
    unsigned short ua = __builtin_bit_cast(unsigned short, (__bf16)a);
    unsigned short ub = __builtin_bit_cast(unsigned short, (__bf16)b);
    return (unsigned)ua | ((unsigned)ub << 16);
}

// Butterfly on DS pipe (__shfl_xor). Permlane-swap substitution failed 4x
// (r10-r13): its row-swap pairing is NOT a complementary xor-exchange whose
// two halves sum to the reduction. Do not retry without an isolated unit test.
__device__ __forceinline__ float bfly_add(float v) {
    v += __shfl_xor(v, 16);
    v += __shfl_xor(v, 32);
    return v;
}

// ---------------- precompute: L, spectral-scaled W in bf16 (rows=(d,i), cols=(j,k)) ----------------
__global__ void precompute_kernel(const float* __restrict__ beta,
                                  const float* __restrict__ ls,
                                  const float* __restrict__ basis,
                                  unsigned short* __restrict__ Wb,
                                  float* __restrict__ auxg)
{
    __shared__ float red[256];
    __shared__ float Ls[3], W1s[3];
    int t = threadIdx.x;

    for (int d = 0; d < 3; ++d) {
        red[t] = fabsf(basis[t*3 + d]);
        __syncthreads();
        for (int s = 128; s > 0; s >>= 1) {
            if (t < s) red[t] = fmaxf(red[t], red[t+s]);
            __syncthreads();
        }
        if (t == 0) {
            float L = 1.5f * red[0];
            Ls[d]  = L;
            W1s[d] = PI_F / (2.0f * L);
        }
        __syncthreads();
    }

    float pref[6], l20[6], l21[6], l22[6];
    #pragma unroll
    for (int dd = 0; dd < 6; ++dd) {
        float a = ls[dd*3+0], b = ls[dd*3+1], c = ls[dd*3+2];
        pref[dd] = 3.9685803f * sqrtf(a*b*c);   // (2*pi)^(3/4) * sqrt(prod ls)
        l20[dd] = a*a; l21[dd] = b*b; l22[dd] = c*c;
    }

    for (int idx = t; idx < 96*GKSTR; idx += 256) {
        int n = idx / GKSTR, k = idx - n*GKSTR;
        int d = n >> 4, i = n & 15;
        float v = 0.0f;
        if (i < 12 && k < 144) {
            int j = k / 12, kk = k - (k/12)*12;
            float o0 = W1s[0]*(float)(i+1);
            float o1 = W1s[1]*(float)(j+1);
            float o2 = W1s[2]*(float)(kk+1);
            float e = expf(-0.25f*(o0*o0*l20[d] + o1*o1*l21[d] + o2*o2*l22[d]));
            v = beta[d*1728 + i*144 + k] * pref[d] * e;
        }
        Wb[idx] = __builtin_bit_cast(unsigned short, (__bf16)v);
    }

    if (t < 3) {
        auxg[t]     = Ls[t];
        auxg[3 + t] = W1s[t];
        auxg[6 + t] = 1.0f / sqrtf(Ls[t]);
    }
}

// ---------------- main fused RK4 integrator: 2-phase software pipeline ----------------
// Waves 0-3 = "owners": RK4 state (8 replicas/pt), epilogue(g-1) in X.
// Waves 4-11: P1(g) in X, trig(g+1) in Y (from qs LDS, written by owners in X).
// All 12 waves: GEMM(g)+stage-2 in Y.
// Double buffers: tabs[2], scr[2]. P single-buffered.
// NOTE: __launch_bounds__ 2nd arg empirically acts like blocks/CU (r4: (384,6)->spill;
// r8: (1024,4)->VGPR 64 + 46MB scratch). Use max-threads only: 768 thr forces cap 170.
__global__ void __launch_bounds__(NTHR) geodesic_kernel(
    const float* __restrict__ pos0, const float* __restrict__ vel0,
    const unsigned short* __restrict__ Wbg, const float* __restrict__ auxg,
    float* __restrict__ out)
{
    __shared__ __align__(16) __bf16 P[NROW*KSTR];           // 31.5 KB
    __shared__ __align__(16) float tabs[2][PTS][TABSTR];    // 25.6 KB
    __shared__ __align__(16) float scr[2][PTS][28];         // 7.2 KB
    __shared__ float qs[PTS][QSTR];                         // 0.64 KB

    const int tid = threadIdx.x;

    // one-time zero init (pads must stay 0)
    for (int idx = tid; idx < NROW*KSTR/2; idx += NTHR) ((unsigned*)P)[idx] = 0u;
    for (int idx = tid; idx < 2*PTS*TABSTR; idx += NTHR) ((float*)tabs)[idx] = 0.f;

    const float L0 = auxg[0], L1 = auxg[1], L2 = auxg[2];
    const float w10 = auxg[3], w11 = auxg[4], w12 = auxg[5];
    const float isq0 = auxg[6], isq1 = auxg[7], isq2 = auxg[8];

    const int w = tid >> 6, lane = tid & 63;
    // GEMM mapping (all 12 waves)
    const int nt = w >> 1, mb = (w & 1) * 3;
    const int lrow = lane & 15, lkg = lane >> 4;
    const int nn = nt*16 + lrow;
    const int ptn = nn / 3, pn = nn - 3*ptn;

    // W fragments (A-operand), resident all kernel
    bf16x8 wfrag[3][5];
    {
        const __bf16* Wb = (const __bf16*)Wbg;
        #pragma unroll
        for (int mt = 0; mt < 3; ++mt)
            #pragma unroll
            for (int ks = 0; ks < 5; ++ks)
                wfrag[mt][ks] = *(const bf16x8*)(Wb + ((mb+mt)*16 + lrow)*GKSTR + ks*32 + lkg*8);
    }

    // ---- owner state (waves 0-3): point myp, 8 replicas ----
    const bool owner = (w < 4);
    const int  myp = (w << 3) + (lane & 7);
    const int  rep = lane >> 3;                 // 0..7 trig stripe (prologue)
    float px=0,py=0,pz=0, vx=0,vy=0,vz=0, vcx=0,vcy=0,vcz=0;
    float vsx=0,vsy=0,vsz=0, asx=0,asy=0,asz=0;
    float pnx=0,pny=0,pnz=0;                    // pending p_new
    float qnx=0,qny=0,qnz=0;                    // q for stage g+1
    size_t pg3 = 0;

    const float dt  = 1.0f/49.0f;
    const float hdt = 0.5f/49.0f;
    const float sdt = dt/6.0f;

    if (owner) {
        pg3 = (size_t)(blockIdx.x * PTS + myp) * 3u;
        px = pos0[pg3+0]; py = pos0[pg3+1]; pz = pos0[pg3+2];
        vx = vel0[pg3+0]; vy = vel0[pg3+1]; vz = vel0[pg3+2];
        vcx = vx; vcy = vy; vcz = vz;
        qnx = fmaf(hdt,vx,px); qny = fmaf(hdt,vy,py); qnz = fmaf(hdt,vz,pz);  // q(stage1)
        if (lane < 8) {
            qs[myp][0] = qnx; qs[myp][1] = qny; qs[myp][2] = qnz;   // q(1) for Y(0) trig
            out[pg3+0] = px; out[pg3+1] = py; out[pg3+2] = pz;
            out[(size_t)BATCH*3 + pg3 + 0] = vx;
            out[(size_t)BATCH*3 + pg3 + 1] = vy;
            out[(size_t)BATCH*3 + pg3 + 2] = vz;
        }
    }
    __syncthreads();   // zero-init + qs(1) visible

    // prologue: trig(stage 0) with q = p into tabs[0] (owners, from registers)
    if (owner) {
        float* tp = &tabs[0][myp][0];
        #pragma unroll 1
        for (int r = rep; r < 36; r += 8) {
            int d = (r>=24)?2:((r>=12)?1:0);
            int k = r - 12*d;
            float q   = (d==0)?px:((d==1)?py:pz);
            float Ld  = (d==0)?L0:((d==1)?L1:L2);
            float w1d = (d==0)?w10:((d==1)?w11:w12);
            float isd = (d==0)?isq0:((d==1)?isq1:isq2);
            float wk = w1d * (float)(k+1);
            float sn, cs;
            __sincosf(wk*(q + Ld), &sn, &cs);
            int offs = (d==0)?0:((d==1)?32:56);
            int offc = offs + ((d==0)?16:12);
            tp[offs+k] = isd*sn;
            tp[offc+k] = isd*cs*wk;
        }
    }
    __syncthreads();

    #pragma unroll 1
    for (int g = 0; g <= 196; ++g) {
        const int cb = g & 1;

        // ================= X phase =================
        if (g < 196 && !owner) {
            // P1(g): 768 units over 512 lanes
            int idx = (w-4)*64 + lane;
            #pragma unroll 1
            for (int rr = 0; rr < 2; ++rr) {
                int u = idx + rr*512;
                if (rr == 1 && idx >= 256) break;
                int pt = u / 24;
                int role = u - pt*24;
                int j = role >> 1, kb = (role & 1)*6;
                const float* tb = &tabs[cb][pt][0];
                float s1 = tb[32 + j], c1 = tb[44 + j];
                float2 sa = *(const float2*)&tb[56 + kb];
                float2 sb = *(const float2*)&tb[58 + kb];
                float2 sg = *(const float2*)&tb[60 + kb];
                float2 ca = *(const float2*)&tb[68 + kb];
                float2 cbv = *(const float2*)&tb[70 + kb];
                float2 cg = *(const float2*)&tb[72 + kb];
                float s2v[6] = {sa.x, sa.y, sb.x, sb.y, sg.x, sg.y};
                float c2v[6] = {ca.x, ca.y, cbv.x, cbv.y, cg.x, cg.y};
                int colb = j*12 + kb;
                unsigned* pss = (unsigned*)&P[(pt*3 + 0)*KSTR + colb];
                unsigned* pcs = (unsigned*)&P[(pt*3 + 1)*KSTR + colb];
                unsigned* psc = (unsigned*)&P[(pt*3 + 2)*KSTR + colb];
                #pragma unroll
                for (int u2 = 0; u2 < 3; ++u2) {
                    pss[u2] = pack2bf(s1*s2v[2*u2], s1*s2v[2*u2+1]);
                    pcs[u2] = pack2bf(c1*s2v[2*u2], c1*s2v[2*u2+1]);
                    psc[u2] = pack2bf(s1*c2v[2*u2], s1*c2v[2*u2+1]);
                }
            }
        }
        if (g > 0 && owner) {
            // epilogue(g-1): accel at stage sp with velocity vc, from scr[(g-1)&1]
            const int sp = (g-1) & 3;
            const f32x4* spr = (const f32x4*)&scr[cb^1][myp][0];
            f32x4 q0 = spr[0], q1 = spr[1], q2 = spr[2], q3 = spr[3], q4 = spr[4], q5 = spr[5];

            float ux = vcx, uy = vcy, uz = vcz;

            float g00 = q0[0]+1.f, g10 = q0[1], g11 = q0[2]+1.f;
            float g20 = q0[3], g21 = q1[0], g22 = q1[1]+1.f;
            float d0a0=q1[2], d0a1=q1[3], d0a2=q2[0], d0a3=q2[1], d0a4=q2[2], d0a5=q2[3];
            float d1a0=q3[0], d1a1=q3[1], d1a2=q3[2], d1a3=q3[3], d1a4=q4[0], d1a5=q4[1];
            float d2a0=q4[2], d2a1=q4[3], d2a2=q5[0], d2a3=q5[1], d2a4=q5[2], d2a5=q5[3];

            float a00 = g11*g22 - g21*g21;
            float a01 = g20*g21 - g10*g22;
            float a02 = g10*g21 - g20*g11;
            float a11 = g00*g22 - g20*g20;
            float a12 = g10*g20 - g00*g21;
            float a22 = g00*g11 - g10*g10;
            float det = g00*a00 + g10*a01 + g20*a02;
            float inv = 1.0f / det;
            float h00=a00*inv, h01=a01*inv, h02=a02*inv;
            float h11=a11*inv, h12=a12*inv, h22=a22*inv;

            float t0 = ux*d0a0 + uy*d1a0 + uz*d2a0;
            float t1 = ux*d0a1 + uy*d1a1 + uz*d2a1;
            float t2 = ux*d0a2 + uy*d1a2 + uz*d2a2;
            float t3 = ux*d0a3 + uy*d1a3 + uz*d2a3;
            float t4 = ux*d0a4 + uy*d1a4 + uz*d2a4;
            float t5 = ux*d0a5 + uy*d1a5 + uz*d2a5;

            float hl0 = ux*t0 + uy*t1 + uz*t3;
            float hl1 = ux*t1 + uy*t2 + uz*t4;
            float hl2 = ux*t3 + uy*t4 + uz*t5;

            float xx = ux*ux, yy = uy*uy, zz = uz*uz;
            float xy2 = 2.f*ux*uy, xz2 = 2.f*ux*uz, yz2 = 2.f*uy*uz;
            float e0 = xx*d0a0 + xy2*d0a1 + yy*d0a2 + xz2*d0a3 + yz2*d0a4 + zz*d0a5;
            float e1 = xx*d1a0 + xy2*d1a1 + yy*d1a2 + xz2*d1a3 + yz2*d1a4 + zz*d1a5;
            float e2 = xx*d2a0 + xy2*d2a1 + yy*d2a2 + xz2*d2a3 + yz2*d2a4 + zz*d2a5;

            float C0 = hl0 - 0.5f*e0;
            float C1 = hl1 - 0.5f*e1;
            float C2 = hl2 - 0.5f*e2;
            float ax = -(h00*C0 + h01*C1 + h02*C2);
            float ay = -(h01*C0 + h11*C1 + h12*C2);
            float az = -(h02*C0 + h12*C1 + h22*C2);

            const float wgt = (sp == 1 || sp == 2) ? 2.f : 1.f;
            vsx += wgt*vcx; vsy += wgt*vcy; vsz += wgt*vcz;
            asx += wgt*ax;  asy += wgt*ay;  asz += wgt*az;

            if (sp == 0) {
                vcx = fmaf(hdt,ax,vx); vcy = fmaf(hdt,ay,vy); vcz = fmaf(hdt,az,vz);   // v2
                qnx = fmaf(hdt,vcx,px); qny = fmaf(hdt,vcy,py); qnz = fmaf(hdt,vcz,pz); // q3
            } else if (sp == 1) {
                vcx = fmaf(hdt,ax,vx); vcy = fmaf(hdt,ay,vy); vcz = fmaf(hdt,az,vz);   // v3
                qnx = fmaf(dt,vcx,px); qny = fmaf(dt,vcy,py); qnz = fmaf(dt,vcz,pz);   // q4
            } else if (sp == 2) {
                vcx = fmaf(dt,ax,vx); vcy = fmaf(dt,ay,vy); vcz = fmaf(dt,az,vz);      // v4
                pnx = fmaf(sdt, vsx+vcx, px);    // p_new needs only velocities
                pny = fmaf(sdt, vsy+vcy, py);
                pnz = fmaf(sdt, vsz+vcz, pz);
                qnx = pnx; qny = pny; qnz = pnz; // q(stage0, next step)
            } else {
                vx = fmaf(sdt, asx, vx); vy = fmaf(sdt, asy, vy); vz = fmaf(sdt, asz, vz);
                px = pnx; py = pny; pz = pnz;
                vcx = vx; vcy = vy; vcz = vz;
                qnx = fmaf(hdt,vx,px); qny = fmaf(hdt,vy,py); qnz = fmaf(hdt,vz,pz);   // q1 next step
                vsx=vsy=vsz=0.f; asx=asy=asz=0.f;
                if (lane < 8) {
                    int step = (g-1) >> 2;
                    size_t ob = (size_t)(step+1) * 2u * BATCH * 3u;
                    out[ob + pg3 + 0] = px;
                    out[ob + pg3 + 1] = py;
                    out[ob + pg3 + 2] = pz;
                    out[ob + (size_t)BATCH*3 + pg3 + 0] = vx;
                    out[ob + (size_t)BATCH*3 + pg3 + 1] = vy;
                    out[ob + (size_t)BATCH*3 + pg3 + 2] = vz;
                }
            }
            if (lane < 8) {   // publish q(g+1) for the non-owner trig in Y
                qs[myp][0] = qnx; qs[myp][1] = qny; qs[myp][2] = qnz;
            }
        }
        __syncthreads();   // BX

        if (g == 196) break;

        // ================= Y phase =================
        if (!owner) {
            // trig(g+1) from qs -> tabs[cb^1]; 1152 units over 512 lanes
            int base = (w-4)*64 + lane;
            #pragma unroll 1
            for (int u = base; u < 1152; u += 512) {
                int pt = u / 36;
                int r  = u - 36*pt;
                int d  = (r>=24)?2:((r>=12)?1:0);
                int k  = r - 12*d;
                float q   = qs[pt][d];
                float Ld  = (d==0)?L0:((d==1)?L1:L2);
                float w1d = (d==0)?w10:((d==1)?w11:w12);
                float isd = (d==0)?isq0:((d==1)?isq1:isq2);
                float wk = w1d * (float)(k+1);
                float sn, cs;
                __sincosf(wk*(q + Ld), &sn, &cs);
                int offs = (d==0)?0:((d==1)?32:56);
                int offc = offs + ((d==0)?16:12);
                tabs[cb^1][pt][offs+k] = isd*sn;
                tabs[cb^1][pt][offc+k] = isd*cs*wk;
            }
        }
        // GEMM(g) + stage-2 (all 12 waves)
        {
            f32x4 acc0 = {0.f,0.f,0.f,0.f}, acc1 = {0.f,0.f,0.f,0.f}, acc2 = {0.f,0.f,0.f,0.f};
            #pragma unroll
            for (int ks = 0; ks < 5; ++ks) {
                bf16x8 pf = *(const bf16x8*)&P[nn*KSTR + ks*32 + lkg*8];
                acc0 = __builtin_amdgcn_mfma_f32_16x16x32_bf16(wfrag[0][ks], pf, acc0, 0, 0, 0);
                acc1 = __builtin_amdgcn_mfma_f32_16x16x32_bf16(wfrag[1][ks], pf, acc1, 0, 0, 0);
                acc2 = __builtin_amdgcn_mfma_f32_16x16x32_bf16(wfrag[2][ks], pf, acc2, 0, 0, 0);
            }

            f32x4 s0v = *(const f32x4*)&tabs[cb][ptn][lkg*4];
            f32x4 c0v = *(const f32x4*)&tabs[cb][ptn][16 + lkg*4];

            float vs0 = acc0[0]*s0v[0] + acc0[1]*s0v[1] + acc0[2]*s0v[2] + acc0[3]*s0v[3];
            float vs1 = acc1[0]*s0v[0] + acc1[1]*s0v[1] + acc1[2]*s0v[2] + acc1[3]*s0v[3];
            float vs2 = acc2[0]*s0v[0] + acc2[1]*s0v[1] + acc2[2]*s0v[2] + acc2[3]*s0v[3];
            float vc0 = acc0[0]*c0v[0] + acc0[1]*c0v[1] + acc0[2]*c0v[2] + acc0[3]*c0v[3];
            float vc1 = acc1[0]*c0v[0] + acc1[1]*c0v[1] + acc1[2]*c0v[2] + acc1[3]*c0v[3];
            float vc2 = acc2[0]*c0v[0] + acc2[1]*c0v[1] + acc2[2]*c0v[2] + acc2[3]*c0v[3];

            vs0 = bfly_add(vs0); vs1 = bfly_add(vs1); vs2 = bfly_add(vs2);
            vc0 = bfly_add(vc0); vc1 = bfly_add(vc1); vc2 = bfly_add(vc2);

            // scr layout: [0:6) gf | [6:12) d0a | [12:18) d1a | [18:24) d2a
            if (lkg == 0) {
                int off = (pn == 0) ? 0 : ((pn == 1) ? 12 : 18);
                scr[cb][ptn][off + mb + 0] = vs0;
                scr[cb][ptn][off + mb + 1] = vs1;
                scr[cb][ptn][off + mb + 2] = vs2;
            }
            if (lkg == 1 && pn == 0) {
                scr[cb][ptn][6 + mb + 0] = vc0;
                scr[cb][ptn][6 + mb + 1] = vc1;
                scr[cb][ptn][6 + mb + 2] = vc2;
            }
        }
        __syncthreads();   // BY
    }
}

extern "C" void kernel_launch(void* const* d_in, const int* in_sizes, int n_in,
                              void* d_out, int out_size, void* d_ws, size_t ws_size,
                              hipStream_t stream) {
    (void)in_sizes; (void)n_in; (void)out_size; (void)ws_size;
    const float* pos0  = (const float*)d_in[0];
    const float* vel0  = (const float*)d_in[1];
    const float* beta  = (const float*)d_in[2];
    const float* ls    = (const float*)d_in[3];
    const float* basis = (const float*)d_in[4];
    float* outp = (float*)d_out;

    unsigned short* Wb = (unsigned short*)d_ws;                 // 96*160 bf16
    float* auxg = (float*)((char*)d_ws + 96*GKSTR*sizeof(unsigned short));

    precompute_kernel<<<1, 256, 0, stream>>>(beta, ls, basis, Wb, auxg);
    geodesic_kernel<<<BATCH/PTS, NTHR, 0, stream>>>(pos0, vel0, Wb, auxg, outp);
}

// Round 15
// 411.626 us; speedup vs baseline: 1.0388x; 1.0388x over previous
//
#include <hip/hip_runtime.h>
#include <math.h>

#define BATCH  8192
#define TSTEPS 50
#define PTS    32          // points per block
#define NTHR   1024        // 16 waves (4/SIMD), 1 block/CU
#define KSTR   168         // P lds row stride (bf16 elems)
#define GKSTR  160         // global Wb row stride (bf16, 144 real + 16 zero)
#define TABSTR 100         // tabs row stride (f32)
#define NROW   96          // GEMM N rows = PTS*3
#define PI_F   3.14159265358979323846f

typedef __bf16 bf16x8 __attribute__((ext_vector_type(8)));
typedef float  f32x4  __attribute__((ext_vector_type(4)));

__device__ __forceinline__ unsigned pack2bf(float a, float b) {
    unsigned short ua = __builtin_bit_cast(unsigned short, (__bf16)a);
    unsigned short ub = __builtin_bit_cast(unsigned short, (__bf16)b);
    return (unsigned)ua | ((unsigned)ub << 16);
}

// Butterfly on DS pipe (__shfl_xor). Permlane-swap substitution failed 4x
// (r10-r13): its row-swap pairing is NOT a complementary xor-exchange whose
// two halves sum to the reduction. Do not retry without an isolated unit test.
__device__ __forceinline__ float bfly_add(float v) {
    v += __shfl_xor(v, 16);
    v += __shfl_xor(v, 32);
    return v;
}

// ---------------- precompute: L, spectral-scaled W in bf16 (rows=(d,i), cols=(j,k)) ----------------
__global__ void precompute_kernel(const float* __restrict__ beta,
                                  const float* __restrict__ ls,
                                  const float* __restrict__ basis,
                                  unsigned short* __restrict__ Wb,
                                  float* __restrict__ auxg)
{
    __shared__ float red[256];
    __shared__ float Ls[3], W1s[3];
    int t = threadIdx.x;

    for (int d = 0; d < 3; ++d) {
        red[t] = fabsf(basis[t*3 + d]);
        __syncthreads();
        for (int s = 128; s > 0; s >>= 1) {
            if (t < s) red[t] = fmaxf(red[t], red[t+s]);
            __syncthreads();
        }
        if (t == 0) {
            float L = 1.5f * red[0];
            Ls[d]  = L;
            W1s[d] = PI_F / (2.0f * L);
        }
        __syncthreads();
    }

    float pref[6], l20[6], l21[6], l22[6];
    #pragma unroll
    for (int dd = 0; dd < 6; ++dd) {
        float a = ls[dd*3+0], b = ls[dd*3+1], c = ls[dd*3+2];
        pref[dd] = 3.9685803f * sqrtf(a*b*c);   // (2*pi)^(3/4) * sqrt(prod ls)
        l20[dd] = a*a; l21[dd] = b*b; l22[dd] = c*c;
    }

    for (int idx = t; idx < 96*GKSTR; idx += 256) {
        int n = idx / GKSTR, k = idx - n*GKSTR;
        int d = n >> 4, i = n & 15;
        float v = 0.0f;
        if (i < 12 && k < 144) {
            int j = k / 12, kk = k - (k/12)*12;
            float o0 = W1s[0]*(float)(i+1);
            float o1 = W1s[1]*(float)(j+1);
            float o2 = W1s[2]*(float)(kk+1);
            float e = expf(-0.25f*(o0*o0*l20[d] + o1*o1*l21[d] + o2*o2*l22[d]));
            v = beta[d*1728 + i*144 + k] * pref[d] * e;
        }
        Wb[idx] = __builtin_bit_cast(unsigned short, (__bf16)v);
    }

    if (t < 3) {
        auxg[t]     = Ls[t];
        auxg[3 + t] = W1s[t];
        auxg[6 + t] = 1.0f / sqrtf(Ls[t]);
    }
}

// ---------------- main fused RK4 integrator: 2-phase pipeline, 16 waves ----------------
// Waves 0-11: P1(g) in X (1 unit/lane), GEMM(g)+stage-2 in Y (mapping identical to r9).
// Waves 12-15 = "owners": RK4 state (8 replicas/pt), epilogue(g-1) in X,
// trig(g+1) in Y from registers. Double buffers: tabs[2], scr[2]. P single.
// NOTE: __launch_bounds__ 2nd arg empirically acts like blocks/CU (r4: (384,6)->spill;
// r8: (1024,4)->VGPR 64 + 46MB scratch). ONE arg only: 1024 thr -> VGPR cap 128
// (we use ~76-100, no spill).
__global__ void __launch_bounds__(NTHR) geodesic_kernel(
    const float* __restrict__ pos0, const float* __restrict__ vel0,
    const unsigned short* __restrict__ Wbg, const float* __restrict__ auxg,
    float* __restrict__ out)
{
    __shared__ __align__(16) __bf16 P[NROW*KSTR];           // 31.5 KB
    __shared__ __align__(16) float tabs[2][PTS][TABSTR];    // 25.6 KB
    __shared__ __align__(16) float scr[2][PTS][28];         // 7.2 KB

    const int tid = threadIdx.x;

    // one-time zero init (pads must stay 0)
    for (int idx = tid; idx < NROW*KSTR/2; idx += NTHR) ((unsigned*)P)[idx] = 0u;
    for (int idx = tid; idx < 2*PTS*TABSTR; idx += NTHR) ((float*)tabs)[idx] = 0.f;

    const float L0 = auxg[0], L1 = auxg[1], L2 = auxg[2];
    const float w10 = auxg[3], w11 = auxg[4], w12 = auxg[5];
    const float isq0 = auxg[6], isq1 = auxg[7], isq2 = auxg[8];

    const int w = tid >> 6, lane = tid & 63;
    const bool gemm_wave = (w < 12);
    // GEMM mapping (waves 0-11; identical to r9)
    const int nt = w >> 1, mb = (w & 1) * 3;
    const int lrow = lane & 15, lkg = lane >> 4;
    const int nn = nt*16 + lrow;
    const int ptn = nn / 3, pn = nn - 3*ptn;

    // W fragments (A-operand), resident all kernel (GEMM waves only)
    bf16x8 wfrag[3][5];
    if (gemm_wave) {
        const __bf16* Wb = (const __bf16*)Wbg;
        #pragma unroll
        for (int mt = 0; mt < 3; ++mt)
            #pragma unroll
            for (int ks = 0; ks < 5; ++ks)
                wfrag[mt][ks] = *(const bf16x8*)(Wb + ((mb+mt)*16 + lrow)*GKSTR + ks*32 + lkg*8);
    }

    // ---- owner state (waves 12-15): point myp, 8 replicas ----
    const bool owner = (w >= 12);
    const int  myp = ((w - 12) << 3) + (lane & 7);
    const int  rep = lane >> 3;                 // 0..7 trig stripe
    float px=0,py=0,pz=0, vx=0,vy=0,vz=0, vcx=0,vcy=0,vcz=0;
    float vsx=0,vsy=0,vsz=0, asx=0,asy=0,asz=0;
    float pnx=0,pny=0,pnz=0;                    // pending p_new
    float qnx=0,qny=0,qnz=0;                    // q for stage g+1 (trig input)
    size_t pg3 = 0;

    const float dt  = 1.0f/49.0f;
    const float hdt = 0.5f/49.0f;
    const float sdt = dt/6.0f;

    if (owner) {
        pg3 = (size_t)(blockIdx.x * PTS + myp) * 3u;
        px = pos0[pg3+0]; py = pos0[pg3+1]; pz = pos0[pg3+2];
        vx = vel0[pg3+0]; vy = vel0[pg3+1]; vz = vel0[pg3+2];
        vcx = vx; vcy = vy; vcz = vz;
        qnx = fmaf(hdt,vx,px); qny = fmaf(hdt,vy,py); qnz = fmaf(hdt,vz,pz);  // q(stage1)
        if (lane < 8) {
            out[pg3+0] = px; out[pg3+1] = py; out[pg3+2] = pz;
            out[(size_t)BATCH*3 + pg3 + 0] = vx;
            out[(size_t)BATCH*3 + pg3 + 1] = vy;
            out[(size_t)BATCH*3 + pg3 + 2] = vz;
        }
    }
    __syncthreads();   // zero-init done

    // prologue: trig(stage 0) with q = p into tabs[0] (owners, from registers)
    if (owner) {
        float* tp = &tabs[0][myp][0];
        #pragma unroll 1
        for (int r = rep; r < 36; r += 8) {
            int d = (r>=24)?2:((r>=12)?1:0);
            int k = r - 12*d;
            float q   = (d==0)?px:((d==1)?py:pz);
            float Ld  = (d==0)?L0:((d==1)?L1:L2);
            float w1d = (d==0)?w10:((d==1)?w11:w12);
            float isd = (d==0)?isq0:((d==1)?isq1:isq2);
            float wk = w1d * (float)(k+1);
            float sn, cs;
            __sincosf(wk*(q + Ld), &sn, &cs);
            int offs = (d==0)?0:((d==1)?32:56);
            int offc = offs + ((d==0)?16:12);
            tp[offs+k] = isd*sn;
            tp[offc+k] = isd*cs*wk;
        }
    }
    __syncthreads();

    #pragma unroll 1
    for (int g = 0; g <= 196; ++g) {
        const int cb = g & 1;

        // ================= X phase =================
        if (g < 196 && gemm_wave) {
            // P1(g): 768 units over 768 lanes — exactly one per lane
            int u = tid;
            int pt = u / 24;
            int role = u - pt*24;
            int j = role >> 1, kb = (role & 1)*6;
            const float* tb = &tabs[cb][pt][0];
            float s1 = tb[32 + j], c1 = tb[44 + j];
            float2 sa = *(const float2*)&tb[56 + kb];
            float2 sb = *(const float2*)&tb[58 + kb];
            float2 sg = *(const float2*)&tb[60 + kb];
            float2 ca = *(const float2*)&tb[68 + kb];
            float2 cbv = *(const float2*)&tb[70 + kb];
            float2 cg = *(const float2*)&tb[72 + kb];
            float s2v[6] = {sa.x, sa.y, sb.x, sb.y, sg.x, sg.y};
            float c2v[6] = {ca.x, ca.y, cbv.x, cbv.y, cg.x, cg.y};
            int colb = j*12 + kb;
            unsigned* pss = (unsigned*)&P[(pt*3 + 0)*KSTR + colb];
            unsigned* pcs = (unsigned*)&P[(pt*3 + 1)*KSTR + colb];
            unsigned* psc = (unsigned*)&P[(pt*3 + 2)*KSTR + colb];
            #pragma unroll
            for (int u2 = 0; u2 < 3; ++u2) {
                pss[u2] = pack2bf(s1*s2v[2*u2], s1*s2v[2*u2+1]);
                pcs[u2] = pack2bf(c1*s2v[2*u2], c1*s2v[2*u2+1]);
                psc[u2] = pack2bf(s1*c2v[2*u2], s1*c2v[2*u2+1]);
            }
        }
        if (g > 0 && owner) {
            // epilogue(g-1): accel at stage sp with velocity vc, from scr[(g-1)&1]
            const int sp = (g-1) & 3;
            const f32x4* spr = (const f32x4*)&scr[cb^1][myp][0];
            f32x4 q0 = spr[0], q1 = spr[1], q2 = spr[2], q3 = spr[3], q4 = spr[4], q5 = spr[5];

            float ux = vcx, uy = vcy, uz = vcz;

            float g00 = q0[0]+1.f, g10 = q0[1], g11 = q0[2]+1.f;
            float g20 = q0[3], g21 = q1[0], g22 = q1[1]+1.f;
            float d0a0=q1[2], d0a1=q1[3], d0a2=q2[0], d0a3=q2[1], d0a4=q2[2], d0a5=q2[3];
            float d1a0=q3[0], d1a1=q3[1], d1a2=q3[2], d1a3=q3[3], d1a4=q4[0], d1a5=q4[1];
            float d2a0=q4[2], d2a1=q4[3], d2a2=q5[0], d2a3=q5[1], d2a4=q5[2], d2a5=q5[3];

            float a00 = g11*g22 - g21*g21;
            float a01 = g20*g21 - g10*g22;
            float a02 = g10*g21 - g20*g11;
            float a11 = g00*g22 - g20*g20;
            float a12 = g10*g20 - g00*g21;
            float a22 = g00*g11 - g10*g10;
            float det = g00*a00 + g10*a01 + g20*a02;
            float inv = 1.0f / det;
            float h00=a00*inv, h01=a01*inv, h02=a02*inv;
            float h11=a11*inv, h12=a12*inv, h22=a22*inv;

            float t0 = ux*d0a0 + uy*d1a0 + uz*d2a0;
            float t1 = ux*d0a1 + uy*d1a1 + uz*d2a1;
            float t2 = ux*d0a2 + uy*d1a2 + uz*d2a2;
            float t3 = ux*d0a3 + uy*d1a3 + uz*d2a3;
            float t4 = ux*d0a4 + uy*d1a4 + uz*d2a4;
            float t5 = ux*d0a5 + uy*d1a5 + uz*d2a5;

            float hl0 = ux*t0 + uy*t1 + uz*t3;
            float hl1 = ux*t1 + uy*t2 + uz*t4;
            float hl2 = ux*t3 + uy*t4 + uz*t5;

            float xx = ux*ux, yy = uy*uy, zz = uz*uz;
            float xy2 = 2.f*ux*uy, xz2 = 2.f*ux*uz, yz2 = 2.f*uy*uz;
            float e0 = xx*d0a0 + xy2*d0a1 + yy*d0a2 + xz2*d0a3 + yz2*d0a4 + zz*d0a5;
            float e1 = xx*d1a0 + xy2*d1a1 + yy*d1a2 + xz2*d1a3 + yz2*d1a4 + zz*d1a5;
            float e2 = xx*d2a0 + xy2*d2a1 + yy*d2a2 + xz2*d2a3 + yz2*d2a4 + zz*d2a5;

            float C0 = hl0 - 0.5f*e0;
            float C1 = hl1 - 0.5f*e1;
            float C2 = hl2 - 0.5f*e2;
            float ax = -(h00*C0 + h01*C1 + h02*C2);
            float ay = -(h01*C0 + h11*C1 + h12*C2);
            float az = -(h02*C0 + h12*C1 + h22*C2);

            const float wgt = (sp == 1 || sp == 2) ? 2.f : 1.f;
            vsx += wgt*vcx; vsy += wgt*vcy; vsz += wgt*vcz;
            asx += wgt*ax;  asy += wgt*ay;  asz += wgt*az;

            if (sp == 0) {
                vcx = fmaf(hdt,ax,vx); vcy = fmaf(hdt,ay,vy); vcz = fmaf(hdt,az,vz);   // v2
                qnx = fmaf(hdt,vcx,px); qny = fmaf(hdt,vcy,py); qnz = fmaf(hdt,vcz,pz); // q3
            } else if (sp == 1) {
                vcx = fmaf(hdt,ax,vx); vcy = fmaf(hdt,ay,vy); vcz = fmaf(hdt,az,vz);   // v3
                qnx = fmaf(dt,vcx,px); qny = fmaf(dt,vcy,py); qnz = fmaf(dt,vcz,pz);   // q4
            } else if (sp == 2) {
                vcx = fmaf(dt,ax,vx); vcy = fmaf(dt,ay,vy); vcz = fmaf(dt,az,vz);      // v4
                pnx = fmaf(sdt, vsx+vcx, px);    // p_new needs only velocities
                pny = fmaf(sdt, vsy+vcy, py);
                pnz = fmaf(sdt, vsz+vcz, pz);
                qnx = pnx; qny = pny; qnz = pnz; // q(stage0, next step)
            } else {
                vx = fmaf(sdt, asx, vx); vy = fmaf(sdt, asy, vy); vz = fmaf(sdt, asz, vz);
                px = pnx; py = pny; pz = pnz;
                vcx = vx; vcy = vy; vcz = vz;
                qnx = fmaf(hdt,vx,px); qny = fmaf(hdt,vy,py); qnz = fmaf(hdt,vz,pz);   // q1 next step
                vsx=vsy=vsz=0.f; asx=asy=asz=0.f;
                if (lane < 8) {
                    int step = (g-1) >> 2;
                    size_t ob = (size_t)(step+1) * 2u * BATCH * 3u;
                    out[ob + pg3 + 0] = px;
                    out[ob + pg3 + 1] = py;
                    out[ob + pg3 + 2] = pz;
                    out[ob + (size_t)BATCH*3 + pg3 + 0] = vx;
                    out[ob + (size_t)BATCH*3 + pg3 + 1] = vy;
                    out[ob + (size_t)BATCH*3 + pg3 + 2] = vz;
                }
            }
        }
        __syncthreads();   // BX

        if (g == 196) break;

        // ================= Y phase =================
        if (owner) {
            // trig(g+1) from register q -> tabs[cb^1]
            float* tp = &tabs[cb^1][myp][0];
            #pragma unroll 1
            for (int r = rep; r < 36; r += 8) {
                int d = (r>=24)?2:((r>=12)?1:0);
                int k = r - 12*d;
                float q   = (d==0)?qnx:((d==1)?qny:qnz);
                float Ld  = (d==0)?L0:((d==1)?L1:L2);
                float w1d = (d==0)?w10:((d==1)?w11:w12);
                float isd = (d==0)?isq0:((d==1)?isq1:isq2);
                float wk = w1d * (float)(k+1);
                float sn, cs;
                __sincosf(wk*(q + Ld), &sn, &cs);
                int offs = (d==0)?0:((d==1)?32:56);
                int offc = offs + ((d==0)?16:12);
                tp[offs+k] = isd*sn;
                tp[offc+k] = isd*cs*wk;
            }
        } else {
            // GEMM(g) + stage-2 (waves 0-11)
            f32x4 acc0 = {0.f,0.f,0.f,0.f}, acc1 = {0.f,0.f,0.f,0.f}, acc2 = {0.f,0.f,0.f,0.f};
            #pragma unroll
            for (int ks = 0; ks < 5; ++ks) {
                bf16x8 pf = *(const bf16x8*)&P[nn*KSTR + ks*32 + lkg*8];
                acc0 = __builtin_amdgcn_mfma_f32_16x16x32_bf16(wfrag[0][ks], pf, acc0, 0, 0, 0);
                acc1 = __builtin_amdgcn_mfma_f32_16x16x32_bf16(wfrag[1][ks], pf, acc1, 0, 0, 0);
                acc2 = __builtin_amdgcn_mfma_f32_16x16x32_bf16(wfrag[2][ks], pf, acc2, 0, 0, 0);
            }

            f32x4 s0v = *(const f32x4*)&tabs[cb][ptn][lkg*4];
            f32x4 c0v = *(const f32x4*)&tabs[cb][ptn][16 + lkg*4];

            float vs0 = acc0[0]*s0v[0] + acc0[1]*s0v[1] + acc0[2]*s0v[2] + acc0[3]*s0v[3];
            float vs1 = acc1[0]*s0v[0] + acc1[1]*s0v[1] + acc1[2]*s0v[2] + acc1[3]*s0v[3];
            float vs2 = acc2[0]*s0v[0] + acc2[1]*s0v[1] + acc2[2]*s0v[2] + acc2[3]*s0v[3];
            float vc0 = acc0[0]*c0v[0] + acc0[1]*c0v[1] + acc0[2]*c0v[2] + acc0[3]*c0v[3];
            float vc1 = acc1[0]*c0v[0] + acc1[1]*c0v[1] + acc1[2]*c0v[2] + acc1[3]*c0v[3];
            float vc2 = acc2[0]*c0v[0] + acc2[1]*c0v[1] + acc2[2]*c0v[2] + acc2[3]*c0v[3];

            vs0 = bfly_add(vs0); vs1 = bfly_add(vs1); vs2 = bfly_add(vs2);
            vc0 = bfly_add(vc0); vc1 = bfly_add(vc1); vc2 = bfly_add(vc2);

            // scr layout: [0:6) gf | [6:12) d0a | [12:18) d1a | [18:24) d2a
            if (lkg == 0) {
                int off = (pn == 0) ? 0 : ((pn == 1) ? 12 : 18);
                scr[cb][ptn][off + mb + 0] = vs0;
                scr[cb][ptn][off + mb + 1] = vs1;
                scr[cb][ptn][off + mb + 2] = vs2;
            }
            if (lkg == 1 && pn == 0) {
                scr[cb][ptn][6 + mb + 0] = vc0;
                scr[cb][ptn][6 + mb + 1] = vc1;
                scr[cb][ptn][6 + mb + 2] = vc2;
            }
        }
        __syncthreads();   // BY
    }
}

extern "C" void kernel_launch(void* const* d_in, const int* in_sizes, int n_in,
                              void* d_out, int out_size, void* d_ws, size_t ws_size,
                              hipStream_t stream) {
    (void)in_sizes; (void)n_in; (void)out_size; (void)ws_size;
    const float* pos0  = (const float*)d_in[0];
    const float* vel0  = (const float*)d_in[1];
    const float* beta  = (const float*)d_in[2];
    const float* ls    = (const float*)d_in[3];
    const float* basis = (const float*)d_in[4];
    float* outp = (float*)d_out;

    unsigned short* Wb = (unsigned short*)d_ws;                 // 96*160 bf16
    float* auxg = (float*)((char*)d_ws + 96*GKSTR*sizeof(unsigned short));

    precompute_kernel<<<1, 256, 0, stream>>>(beta, ls, basis, Wb, auxg);
    geodesic_kernel<<<BATCH/PTS, NTHR, 0, stream>>>(pos0, vel0, Wb, auxg, outp);
}